// Round 8
// baseline (1198.165 us; speedup 1.0000x reference)
//
#include <hip/hip_runtime.h>
#include <hip/hip_bf16.h>

#define NV 3
#define NPTS 32768
#define C2C 256
#define C3C 32
#define CINC 288
#define CINP 320
#define HH 128
#define WWW 128
#define DDD 32

typedef short bh8 __attribute__((ext_vector_type(8)));
typedef float fx4 __attribute__((ext_vector_type(4)));
typedef unsigned short us4 __attribute__((ext_vector_type(4)));

__device__ __forceinline__ float b2f(unsigned short u) {
    unsigned int x = ((unsigned int)u) << 16;
    return __uint_as_float(x);
}
__device__ __forceinline__ unsigned short f2b(float f) {
    unsigned int x = __float_as_uint(f);
    unsigned int r = (x + 0x7FFFu + ((x >> 16) & 1u)) >> 16;
    return (unsigned short)r;
}

__device__ __forceinline__ void gl2lds16(const unsigned short* g, unsigned short* l) {
    __builtin_amdgcn_global_load_lds(
        (const __attribute__((address_space(1))) unsigned int*)g,
        (__attribute__((address_space(3))) unsigned int*)l, 16, 0, 0);
}

// bijective XCD-aware block swizzle (m204)
__device__ __forceinline__ int xcd_swz(int orig, int nwg) {
    int xcd = orig & 7;
    int q = nwg >> 3, r = nwg & 7;
    int base = (xcd < r) ? xcd * (q + 1) : r * (q + 1) + (xcd - r) * q;
    return base + (orig >> 3);
}

// ---------------- weight f32 -> bf16 with zero stripe at k=288..319 ----------------
__global__ void k_wpad(const float* __restrict__ src, unsigned short* __restrict__ dst, int M, int Kp) {
    int idx = blockIdx.x * 256 + threadIdx.x;
    if (idx >= M * Kp) return;
    int m = idx / Kp, k = idx - m * Kp;
    int Ksrc = Kp - 32;
    float v;
    if (k < CINC) v = src[(size_t)m * Ksrc + k];
    else if (k < CINP) v = 0.0f;
    else v = src[(size_t)m * Ksrc + (k - 32)];
    dst[idx] = f2b(v);
}

// ---------------- img (V,C2,H,W) f32 -> (V,H,W,C2) bf16 ----------------
__global__ void k_timg(const float* __restrict__ in, unsigned short* __restrict__ out) {
    int v = blockIdx.x >> 7, y = blockIdx.x & 127;
    int x0 = blockIdx.y << 6, c0 = blockIdx.z << 6;
    __shared__ float t[64][65];
    int tx = threadIdx.x & 63, tg = threadIdx.x >> 6;
    const float* src = in + (((size_t)(v * C2C + c0) * HH + y) * WWW + x0);
#pragma unroll
    for (int i = 0; i < 16; i++) {
        int cl = tg * 16 + i;
        t[cl][tx] = src[(size_t)cl * (HH * WWW) + tx];
    }
    __syncthreads();
    unsigned short* dst = out + ((size_t)(v * HH + y) * WWW + x0) * C2C + c0;
#pragma unroll
    for (int i = 0; i < 16; i++) {
        int xl = tg * 16 + i;
        dst[(size_t)xl * C2C + tx] = f2b(t[tx][xl]);
    }
}

// ---------------- vol (V,C3,32,32,32) f32 -> (V,32768,C3) bf16 ----------------
__global__ void k_tvol(const float* __restrict__ in, unsigned short* __restrict__ out) {
    int v = blockIdx.x;
    int s0 = blockIdx.y << 8;
    __shared__ float t[32][257];
    int tid = threadIdx.x;
    const float* src = in + (size_t)v * C3C * 32768 + s0;
#pragma unroll
    for (int c = 0; c < 32; c++) t[c][tid] = src[(size_t)c * 32768 + tid];
    __syncthreads();
    unsigned short* dst = out + ((size_t)v * 32768 + s0) * C3C;
    int c = tid & 31, sb = tid >> 5;
#pragma unroll
    for (int j = 0; j < 32; j++) {
        int sl = j * 8 + sb;
        dst[(size_t)sl * C3C + c] = f2b(t[c][sl]);
    }
}

// ---------------- sampler: wave per (point,view), writes 320-wide padded rows ----------------
__global__ __launch_bounds__(256) void k_sample(const float* __restrict__ pts, const float* __restrict__ proj,
                         const unsigned short* __restrict__ imgT, const unsigned short* __restrict__ volT,
                         unsigned short* __restrict__ ptT, int n0, int Nk) {
    int w = threadIdx.x >> 6, l = threadIdx.x & 63;
    int i = blockIdx.x * 4 + w;
    int v = blockIdx.y;
    int n = n0 + i;
    unsigned short* dstRow = ptT + (size_t)(v * Nk + i) * CINP;

    {
        float gx = proj[n * 2 + 0], gy = proj[n * 2 + 1];
        float ix = fminf(fmaxf(((gx + 1.0f) * (float)WWW - 1.0f) * 0.5f, 0.0f), (float)(WWW - 1));
        float iy = fminf(fmaxf(((gy + 1.0f) * (float)HH - 1.0f) * 0.5f, 0.0f), (float)(HH - 1));
        float x0f = floorf(ix), y0f = floorf(iy);
        float wx = ix - x0f, wy = iy - y0f;
        int x0 = (int)x0f, y0 = (int)y0f;
        int x1 = min(x0 + 1, WWW - 1), y1 = min(y0 + 1, HH - 1);
        const unsigned short* base = imgT + (size_t)v * HH * WWW * C2C;
        us4 a = *((const us4*)(base + ((size_t)(y0 * WWW + x0)) * C2C) + l);
        us4 b = *((const us4*)(base + ((size_t)(y0 * WWW + x1)) * C2C) + l);
        us4 c = *((const us4*)(base + ((size_t)(y1 * WWW + x0)) * C2C) + l);
        us4 d = *((const us4*)(base + ((size_t)(y1 * WWW + x1)) * C2C) + l);
        float w00 = (1.0f - wy) * (1.0f - wx), w01 = (1.0f - wy) * wx;
        float w10 = wy * (1.0f - wx), w11 = wy * wx;
        us4 rv;
#pragma unroll
        for (int r = 0; r < 4; r++) {
            float f = b2f(a[r]) * w00 + b2f(b[r]) * w01 + b2f(c[r]) * w10 + b2f(d[r]) * w11;
            rv[r] = f2b(f);
        }
        *(us4*)(dstRow + l * 4) = rv;
    }
    {
        float gx = pts[n * 3 + 0] * 2.0f, gy = pts[n * 3 + 1] * 2.0f, gz = pts[n * 3 + 2] * 2.0f;
        float ix = fminf(fmaxf(((gx + 1.0f) * (float)DDD - 1.0f) * 0.5f, 0.0f), (float)(DDD - 1));
        float iy = fminf(fmaxf(((gy + 1.0f) * (float)DDD - 1.0f) * 0.5f, 0.0f), (float)(DDD - 1));
        float iz = fminf(fmaxf(((gz + 1.0f) * (float)DDD - 1.0f) * 0.5f, 0.0f), (float)(DDD - 1));
        float x0f = floorf(ix), y0f = floorf(iy), z0f = floorf(iz);
        float wx = ix - x0f, wy = iy - y0f, wz = iz - z0f;
        int x0 = (int)x0f, y0 = (int)y0f, z0 = (int)z0f;
        int x1 = min(x0 + 1, DDD - 1), y1 = min(y0 + 1, DDD - 1), z1 = min(z0 + 1, DDD - 1);
        int c = l & 31, zs = l >> 5;
        int zi = zs ? z1 : z0;
        float wzs = zs ? wz : (1.0f - wz);
        const unsigned short* base = volT + (size_t)v * 32768 * C3C;
        float f00 = b2f(base[((size_t)((zi * 32 + y0) * 32 + x0)) * C3C + c]);
        float f01 = b2f(base[((size_t)((zi * 32 + y0) * 32 + x1)) * C3C + c]);
        float f10 = b2f(base[((size_t)((zi * 32 + y1) * 32 + x0)) * C3C + c]);
        float f11 = b2f(base[((size_t)((zi * 32 + y1) * 32 + x1)) * C3C + c]);
        float r = (f00 * (1.0f - wy) * (1.0f - wx) + f01 * (1.0f - wy) * wx +
                   f10 * wy * (1.0f - wx) + f11 * wy * wx) * wzs;
        float other = __shfl_xor(r, 32);
        r += other;
        if (zs == 0) dstRow[C2C + c] = f2b(r);
    }
    if (l < 8) *(us4*)(dstRow + CINC + l * 4) = (us4){0, 0, 0, 0};
}

// ---------------- FUSED layers 0+1: o1 = lrelu(W1 @ [ptT; lrelu(W0 @ ptT + b0)] + b1) ----------------
// Block: 128 columns × all 512 o1 rows. o0 (1024 ch) never touches global memory.
// LDS: Bt = ptT tile [128][320] (swizzled, 80 KB), Ps = P slab [128col][128ch] (swizzled, 32 KB).
__global__ __launch_bounds__(512) void k_g01(const unsigned short* __restrict__ W0,  // [1024][320]
                                             const unsigned short* __restrict__ W1,  // [512][1344]
                                             const unsigned short* __restrict__ Bp,  // ptT [NC][320]
                                             const float* __restrict__ b0,
                                             const float* __restrict__ b1,
                                             unsigned short* __restrict__ C) {       // o1 [NC][512]
    __shared__ unsigned short Bt[128 * 320];
    __shared__ unsigned short Ps[128 * 128];
    int tid = threadIdx.x;
    int w = tid >> 6, l = tid & 63;
    int la = l & 15, lg = l >> 4;
    int bid = xcd_swz(blockIdx.x, gridDim.x);
    int nBlk = bid * 128;

    // stage ptT tile: linear LDS dest, pre-swizzled global source (T2, rule 21)
    {
        const unsigned short* src = Bp + (size_t)nBlk * CINP;
#pragma unroll
        for (int rnd = 0; rnd < 10; rnd++) {
            int f = rnd * 512 + tid;
            int col = f / 40, c = f % 40;
            int cs = (c & ~7) | ((c & 7) ^ (col & 7));
            gl2lds16(src + (size_t)col * CINP + cs * 8, &Bt[f * 8]);
        }
    }
    asm volatile("s_waitcnt vmcnt(0)" ::: "memory");
    __syncthreads();

    fx4 acc[4][8];
#pragma unroll
    for (int rf = 0; rf < 4; rf++)
#pragma unroll
        for (int cf = 0; cf < 8; cf++) acc[rf][cf] = (fx4){0.f, 0.f, 0.f, 0.f};

    for (int j = 0; j < 8; j++) {
        // ---- phase A: P slab j (128 ch × 128 cols); wave w owns ch rows [w*16, w*16+16)
        fx4 pacc[8];
#pragma unroll
        for (int cf = 0; cf < 8; cf++) pacc[cf] = (fx4){0.f, 0.f, 0.f, 0.f};
        const unsigned short* w0row = W0 + (size_t)(j * 128 + w * 16 + la) * CINP;
#pragma unroll
        for (int ks = 0; ks < 10; ks++) {
            bh8 af = *(const bh8*)(w0row + ks * 32 + lg * 8);
#pragma unroll
            for (int cf = 0; cf < 8; cf++) {
                int col = cf * 16 + la;
                int c = ks * 4 + lg;
                int cs = (c & ~7) | ((c & 7) ^ (col & 7));
                bh8 bfr = *(const bh8*)&Bt[col * CINP + cs * 8];
                pacc[cf] = __builtin_amdgcn_mfma_f32_16x16x32_bf16(af, bfr, pacc[cf], 0, 0, 0);
            }
        }
        fx4 bb0 = *(const fx4*)(b0 + j * 128 + w * 16 + lg * 4);
        __syncthreads();  // prior slab's Ps reads complete before overwrite
#pragma unroll
        for (int cf = 0; cf < 8; cf++) {
            int col = cf * 16 + la;
            us4 pv;
#pragma unroll
            for (int r = 0; r < 4; r++) {
                float x = pacc[cf][r] + bb0[r];
                x = (x >= 0.0f) ? x : 0.2f * x;
                pv[r] = f2b(x);
            }
            int c8 = w * 4 + lg;
            int cs = (c8 & ~7) | ((c8 & 7) ^ (col & 7));
            *(us4*)&Ps[col * 128 + cs * 4] = pv;
        }
        __syncthreads();  // Ps slab ready
        // ---- phase B: acc += W1[:, 320+j*128 .. +128] @ P ; wave w owns rows [w*64, +64)
#pragma unroll
        for (int ks = 0; ks < 4; ks++) {
            bh8 af[4];
#pragma unroll
            for (int rf = 0; rf < 4; rf++)
                af[rf] = *(const bh8*)(W1 + (size_t)(w * 64 + rf * 16 + la) * 1344 + CINP + j * 128 + ks * 32 + lg * 8);
#pragma unroll
            for (int cf = 0; cf < 8; cf++) {
                int col = cf * 16 + la;
                int c8 = ks * 8 + lg * 2;
                int cs0 = (c8 & ~7) | ((c8 & 7) ^ (col & 7));
                int cs1 = ((c8 + 1) & ~7) | (((c8 + 1) & 7) ^ (col & 7));
                us4 lo = *(const us4*)&Ps[col * 128 + cs0 * 4];
                us4 hi = *(const us4*)&Ps[col * 128 + cs1 * 4];
                bh8 bfr;
#pragma unroll
                for (int r = 0; r < 4; r++) { bfr[r] = (short)lo[r]; bfr[4 + r] = (short)hi[r]; }
#pragma unroll
                for (int rf = 0; rf < 4; rf++)
                    acc[rf][cf] = __builtin_amdgcn_mfma_f32_16x16x32_bf16(af[rf], bfr, acc[rf][cf], 0, 0, 0);
            }
        }
    }
    // ---- K1 segment: acc += W1[:, 0:320] @ ptT (from Bt)
#pragma unroll
    for (int ks = 0; ks < 10; ks++) {
        bh8 af[4];
#pragma unroll
        for (int rf = 0; rf < 4; rf++)
            af[rf] = *(const bh8*)(W1 + (size_t)(w * 64 + rf * 16 + la) * 1344 + ks * 32 + lg * 8);
#pragma unroll
        for (int cf = 0; cf < 8; cf++) {
            int col = cf * 16 + la;
            int c = ks * 4 + lg;
            int cs = (c & ~7) | ((c & 7) ^ (col & 7));
            bh8 bfr = *(const bh8*)&Bt[col * CINP + cs * 8];
#pragma unroll
            for (int rf = 0; rf < 4; rf++)
                acc[rf][cf] = __builtin_amdgcn_mfma_f32_16x16x32_bf16(af[rf], bfr, acc[rf][cf], 0, 0, 0);
        }
    }
    // ---- epilogue
#pragma unroll
    for (int rf = 0; rf < 4; rf++) {
        int m0 = w * 64 + rf * 16 + lg * 4;
        fx4 bb = *(const fx4*)(b1 + m0);
#pragma unroll
        for (int cf = 0; cf < 8; cf++) {
            int n = nBlk + cf * 16 + la;
            us4 rv;
#pragma unroll
            for (int r = 0; r < 4; r++) {
                float x = acc[rf][cf][r] + bb[r];
                x = (x >= 0.0f) ? x : 0.2f * x;
                rv[r] = f2b(x);
            }
            *(us4*)(C + (size_t)n * 512 + m0) = rv;
        }
    }
}

// ---------------- 128x128 2-phase GEMM body, compile-time K1/K2/M ----------------
template <int K1, int K2, int M>
__device__ __forceinline__ void gemm128_body(const unsigned short* __restrict__ A,
                                             const unsigned short* __restrict__ B1,
                                             const unsigned short* __restrict__ B2,
                                             const float* __restrict__ bias,
                                             unsigned short* __restrict__ C) {
    constexpr int K = K1 + K2;
    __shared__ unsigned short Ash[128 * 32];
    __shared__ unsigned short Bsh[128 * 32];
    int tid = threadIdx.x;
    int w = tid >> 6, l = tid & 63;
    int la = l & 15, lg = l >> 4;
    int wm = w & 1, wn = w >> 1;
    int gx = gridDim.x;
    int nwg = gx * gridDim.y;
    int bid = xcd_swz(blockIdx.y * gx + blockIdx.x, nwg);
    int mBlk = (bid % gx) * 128;
    int nBlk = (bid / gx) * 128;

    int sRow = l >> 2;
    int sCol = (l & 3) * 8;

    fx4 acc[4][4];
#pragma unroll
    for (int mi = 0; mi < 4; mi++)
#pragma unroll
        for (int ni = 0; ni < 4; ni++) acc[mi][ni] = (fx4){0.f, 0.f, 0.f, 0.f};

    const unsigned short* Ag = A + (size_t)mBlk * K;
    {
        const unsigned short* Bg = B1 + (size_t)nBlk * K1;
        for (int k0 = 0; k0 < K1; k0 += 32) {
#pragma unroll
            for (int j = 0; j < 2; j++) {
                int r = w * 32 + j * 16 + sRow;
                gl2lds16(Ag + (size_t)r * K + k0 + sCol, &Ash[r * 32 + sCol]);
                gl2lds16(Bg + (size_t)r * K1 + k0 + sCol, &Bsh[r * 32 + sCol]);
            }
            __syncthreads();
            bh8 af[4], bfv[4];
#pragma unroll
            for (int mi = 0; mi < 4; mi++) af[mi] = *(const bh8*)&Ash[(wm * 64 + mi * 16 + la) * 32 + lg * 8];
#pragma unroll
            for (int ni = 0; ni < 4; ni++) bfv[ni] = *(const bh8*)&Bsh[(wn * 64 + ni * 16 + la) * 32 + lg * 8];
#pragma unroll
            for (int mi = 0; mi < 4; mi++)
#pragma unroll
                for (int ni = 0; ni < 4; ni++)
                    acc[mi][ni] = __builtin_amdgcn_mfma_f32_16x16x32_bf16(af[mi], bfv[ni], acc[mi][ni], 0, 0, 0);
            __syncthreads();
        }
    }
    if constexpr (K2 > 0) {
        const unsigned short* Bg = B2 + (size_t)nBlk * K2;
        for (int k0 = 0; k0 < K2; k0 += 32) {
#pragma unroll
            for (int j = 0; j < 2; j++) {
                int r = w * 32 + j * 16 + sRow;
                gl2lds16(Ag + (size_t)r * K + K1 + k0 + sCol, &Ash[r * 32 + sCol]);
                gl2lds16(Bg + (size_t)r * K2 + k0 + sCol, &Bsh[r * 32 + sCol]);
            }
            __syncthreads();
            bh8 af[4], bfv[4];
#pragma unroll
            for (int mi = 0; mi < 4; mi++) af[mi] = *(const bh8*)&Ash[(wm * 64 + mi * 16 + la) * 32 + lg * 8];
#pragma unroll
            for (int ni = 0; ni < 4; ni++) bfv[ni] = *(const bh8*)&Bsh[(wn * 64 + ni * 16 + la) * 32 + lg * 8];
#pragma unroll
            for (int mi = 0; mi < 4; mi++)
#pragma unroll
                for (int ni = 0; ni < 4; ni++)
                    acc[mi][ni] = __builtin_amdgcn_mfma_f32_16x16x32_bf16(af[mi], bfv[ni], acc[mi][ni], 0, 0, 0);
            __syncthreads();
        }
    }

#pragma unroll
    for (int mi = 0; mi < 4; mi++) {
        int m0 = mBlk + wm * 64 + mi * 16 + lg * 4;
        fx4 bb = *(const fx4*)(bias + m0);
#pragma unroll
        for (int ni = 0; ni < 4; ni++) {
            int n = nBlk + wn * 64 + ni * 16 + la;
            us4 rv;
#pragma unroll
            for (int r = 0; r < 4; r++) {
                float x = acc[mi][ni][r] + bb[r];
                x = (x >= 0.0f) ? x : 0.2f * x;
                rv[r] = f2b(x);
            }
            *(us4*)(C + (size_t)n * M + m0) = rv;
        }
    }
}

__global__ __launch_bounds__(256) void k_g2(const unsigned short* __restrict__ A, const unsigned short* __restrict__ B1,
                                            const unsigned short* __restrict__ B2, const float* __restrict__ bias,
                                            unsigned short* __restrict__ C) {
    gemm128_body<320, 512, 256>(A, B1, B2, bias, C);
}
__global__ __launch_bounds__(256) void k_g3(const unsigned short* __restrict__ A, const unsigned short* __restrict__ B1,
                                            const unsigned short* __restrict__ B2, const float* __restrict__ bias,
                                            unsigned short* __restrict__ C) {
    gemm128_body<320, 256, 128>(A, B1, B2, bias, C);
}

// ---------------- head: 16 lanes per point, coalesced rows, shuffle reduce ----------------
__global__ __launch_bounds__(256) void k_head(const unsigned short* __restrict__ o3, const float* __restrict__ W4,
                       const float* __restrict__ b4, const int* __restrict__ mn_p,
                       float* __restrict__ out, int n0, int Nk, int level) {
    int wv = threadIdx.x >> 6, l = threadIdx.x & 63;
    int sub = l >> 4, cl = l & 15;
    int i = blockIdx.x * 16 + wv * 4 + sub;
    if (i >= Nk) return;
    int mn = *mn_p;
    if (mn > NV) mn = NV;
    if (mn < 1) mn = 1;
    fx4 w0 = *(const fx4*)(W4 + cl * 8);
    fx4 w1 = *(const fx4*)(W4 + cl * 8 + 4);
    float s = 0.0f;
    for (int v = 0; v < mn; v++) {
        bh8 x = *(const bh8*)(o3 + (size_t)(v * Nk + i) * 128 + cl * 8);
#pragma unroll
        for (int r = 0; r < 4; r++) s += w0[r] * b2f((unsigned short)x[r]);
#pragma unroll
        for (int r = 0; r < 4; r++) s += w1[r] * b2f((unsigned short)x[4 + r]);
    }
#pragma unroll
    for (int m = 1; m < 16; m <<= 1) s += __shfl_xor(s, m);
    if (cl == 0) {
        s = s / (float)mn + b4[0];
        out[(size_t)level * NPTS + n0 + i] = 1.0f / (1.0f + expf(-s));
    }
}

extern "C" void kernel_launch(void* const* d_in, const int* in_sizes, int n_in,
                              void* d_out, int out_size, void* d_ws, size_t ws_size,
                              hipStream_t stream) {
    const float* pts = (const float*)d_in[0];
    const float* proj = (const float*)d_in[1];
    const float* img[2] = {(const float*)d_in[2], (const float*)d_in[3]};
    const float* vol[2] = {(const float*)d_in[4], (const float*)d_in[5]};
    const float* Wf[4] = {(const float*)d_in[6], (const float*)d_in[8], (const float*)d_in[10], (const float*)d_in[12]};
    const float* bf[4] = {(const float*)d_in[7], (const float*)d_in[9], (const float*)d_in[11], (const float*)d_in[13]};
    const float* W4 = (const float*)d_in[14];
    const float* b4 = (const float*)d_in[15];
    const int* mn = (const int*)d_in[16];
    float* out = (float*)d_out;

    const int Kp[4] = {320, 1344, 832, 576};
    const int Msz[4] = {1024, 512, 256, 128};

    char* ws = (char*)d_ws;
    size_t off = 0;
    auto alloc = [&](size_t bytes) -> char* {
        char* p = ws + off;
        off = (off + bytes + 255) & ~(size_t)255;
        return p;
    };

    unsigned short* Wb[4];
    for (int i = 0; i < 4; i++) Wb[i] = (unsigned short*)alloc((size_t)Msz[i] * Kp[i] * 2);
    unsigned short* imgT = (unsigned short*)alloc((size_t)NV * HH * WWW * C2C * 2);
    unsigned short* volT = (unsigned short*)alloc((size_t)NV * 32768 * C3C * 2);
    size_t fixed = off;

    // per-point bytes (no o0 anymore): 3 views * 2B * (320 + 512 + 256 + 128)
    const size_t perPt = (size_t)NV * 2 * (CINP + 512 + 256 + 128);
    int Nk = NPTS;
    if (fixed + (size_t)Nk * perPt + 4096 > ws_size) {
        size_t avail = (ws_size > fixed + 4096) ? (ws_size - fixed - 4096) : 0;
        long nk = (long)(avail / perPt);
        nk = (nk / 512) * 512;
        if (nk < 512) nk = 512;
        if (nk > NPTS) nk = NPTS;
        Nk = (int)nk;
    }
    unsigned short* ptT = (unsigned short*)alloc((size_t)NV * Nk * CINP * 2);
    unsigned short* o1 = (unsigned short*)alloc((size_t)NV * Nk * 512 * 2);
    unsigned short* o2 = (unsigned short*)alloc((size_t)NV * Nk * 256 * 2);
    unsigned short* o3 = (unsigned short*)alloc((size_t)NV * Nk * 128 * 2);

    for (int i = 0; i < 4; i++) {
        int n = Msz[i] * Kp[i];
        k_wpad<<<(n + 255) / 256, 256, 0, stream>>>(Wf[i], Wb[i], Msz[i], Kp[i]);
    }

    for (int lvl = 0; lvl < 2; lvl++) {
        k_timg<<<dim3(NV * HH, WWW / 64, C2C / 64), 256, 0, stream>>>(img[lvl], imgT);
        k_tvol<<<dim3(NV, 32768 / 256), 256, 0, stream>>>(vol[lvl], volT);
        for (int n0 = 0; n0 < NPTS; n0 += Nk) {
            int nk = NPTS - n0 < Nk ? NPTS - n0 : Nk;
            int NC = NV * nk;
            k_sample<<<dim3(nk / 4, NV), 256, 0, stream>>>(pts, proj, imgT, volT, ptT, n0, nk);
            k_g01<<<NC / 128, 512, 0, stream>>>(Wb[0], Wb[1], ptT, bf[0], bf[1], o1);
            k_g2<<<dim3(256 / 128, NC / 128), 256, 0, stream>>>(Wb[2], ptT, o1, bf[2], o2);
            k_g3<<<dim3(128 / 128, NC / 128), 256, 0, stream>>>(Wb[3], ptT, o2, bf[3], o3);
            k_head<<<(nk + 15) / 16, 256, 0, stream>>>(o3, W4, b4, mn, out, n0, nk, lvl);
        }
    }
}

// Round 9
// 1065.186 us; speedup vs baseline: 1.1248x; 1.1248x over previous
//
#include <hip/hip_runtime.h>
#include <hip/hip_bf16.h>

#define NV 3
#define NPTS 32768
#define C2C 256
#define C3C 32
#define CINC 288
#define CINP 320
#define HH 128
#define WWW 128
#define DDD 32

typedef short bh8 __attribute__((ext_vector_type(8)));
typedef float fx4 __attribute__((ext_vector_type(4)));
typedef unsigned short us4 __attribute__((ext_vector_type(4)));

__device__ __forceinline__ float b2f(unsigned short u) {
    unsigned int x = ((unsigned int)u) << 16;
    return __uint_as_float(x);
}
__device__ __forceinline__ unsigned short f2b(float f) {
    unsigned int x = __float_as_uint(f);
    unsigned int r = (x + 0x7FFFu + ((x >> 16) & 1u)) >> 16;
    return (unsigned short)r;
}

__device__ __forceinline__ void gl2lds16(const unsigned short* g, unsigned short* l) {
    __builtin_amdgcn_global_load_lds(
        (const __attribute__((address_space(1))) unsigned int*)g,
        (__attribute__((address_space(3))) unsigned int*)l, 16, 0, 0);
}

// bijective XCD-aware block swizzle (m204)
__device__ __forceinline__ int xcd_swz(int orig, int nwg) {
    int xcd = orig & 7;
    int q = nwg >> 3, r = nwg & 7;
    int base = (xcd < r) ? xcd * (q + 1) : r * (q + 1) + (xcd - r) * q;
    return base + (orig >> 3);
}

// ---------------- all 4 weights f32 -> bf16 padded, one dispatch ----------------
__global__ void k_wpad4(const float* __restrict__ s0, const float* __restrict__ s1,
                        const float* __restrict__ s2, const float* __restrict__ s3,
                        unsigned short* __restrict__ d0, unsigned short* __restrict__ d1,
                        unsigned short* __restrict__ d2, unsigned short* __restrict__ d3) {
    const int Ms[4] = {1024, 512, 256, 128};
    const int Kps[4] = {320, 1344, 832, 576};
    int i = blockIdx.y;
    int M = Ms[i], Kp = Kps[i];
    int idx = blockIdx.x * 256 + threadIdx.x;
    if (idx >= M * Kp) return;
    const float* src = (i == 0) ? s0 : (i == 1) ? s1 : (i == 2) ? s2 : s3;
    unsigned short* dst = (i == 0) ? d0 : (i == 1) ? d1 : (i == 2) ? d2 : d3;
    int m = idx / Kp, k = idx - m * Kp;
    int Ksrc = Kp - 32;
    float v;
    if (k < CINC) v = src[(size_t)m * Ksrc + k];
    else if (k < CINP) v = 0.0f;
    else v = src[(size_t)m * Ksrc + (k - 32)];
    dst[idx] = f2b(v);
}

// ---------------- img (V,C2,H,W) f32 -> (V,H,W,C2) bf16, both levels ----------------
__global__ void k_timg(const float* __restrict__ in0, const float* __restrict__ in1,
                       unsigned short* __restrict__ out, size_t lvlStride) {
    int lvl = blockIdx.z >> 2, cb = blockIdx.z & 3;
    const float* in = lvl ? in1 : in0;
    int v = blockIdx.x >> 7, y = blockIdx.x & 127;
    int x0 = blockIdx.y << 6, c0 = cb << 6;
    __shared__ float t[64][65];
    int tx = threadIdx.x & 63, tg = threadIdx.x >> 6;
    const float* src = in + (((size_t)(v * C2C + c0) * HH + y) * WWW + x0);
#pragma unroll
    for (int i = 0; i < 16; i++) {
        int cl = tg * 16 + i;
        t[cl][tx] = src[(size_t)cl * (HH * WWW) + tx];
    }
    __syncthreads();
    unsigned short* dst = out + lvl * lvlStride + ((size_t)(v * HH + y) * WWW + x0) * C2C + c0;
#pragma unroll
    for (int i = 0; i < 16; i++) {
        int xl = tg * 16 + i;
        dst[(size_t)xl * C2C + tx] = f2b(t[tx][xl]);
    }
}

// ---------------- vol (V,C3,32,32,32) f32 -> (V,32768,C3) bf16, both levels ----------------
__global__ void k_tvol(const float* __restrict__ in0, const float* __restrict__ in1,
                       unsigned short* __restrict__ out, size_t lvlStride) {
    int lvl = blockIdx.z;
    const float* in = lvl ? in1 : in0;
    int v = blockIdx.x;
    int s0 = blockIdx.y << 8;
    __shared__ float t[32][257];
    int tid = threadIdx.x;
    const float* src = in + (size_t)v * C3C * 32768 + s0;
#pragma unroll
    for (int c = 0; c < 32; c++) t[c][tid] = src[(size_t)c * 32768 + tid];
    __syncthreads();
    unsigned short* dst = out + lvl * lvlStride + ((size_t)v * 32768 + s0) * C3C;
    int c = tid & 31, sb = tid >> 5;
#pragma unroll
    for (int j = 0; j < 32; j++) {
        int sl = j * 8 + sb;
        dst[(size_t)sl * C3C + c] = f2b(t[c][sl]);
    }
}

// ---------------- sampler: wave per (point,view), writes 320-wide padded rows ----------------
__global__ __launch_bounds__(256) void k_sample(const float* __restrict__ pts, const float* __restrict__ proj,
                         const unsigned short* __restrict__ imgT, const unsigned short* __restrict__ volT,
                         unsigned short* __restrict__ ptT, int n0, int Nk) {
    int w = threadIdx.x >> 6, l = threadIdx.x & 63;
    int i = blockIdx.x * 4 + w;
    int v = blockIdx.y;
    int n = n0 + i;
    unsigned short* dstRow = ptT + (size_t)(v * Nk + i) * CINP;

    {
        float gx = proj[n * 2 + 0], gy = proj[n * 2 + 1];
        float ix = fminf(fmaxf(((gx + 1.0f) * (float)WWW - 1.0f) * 0.5f, 0.0f), (float)(WWW - 1));
        float iy = fminf(fmaxf(((gy + 1.0f) * (float)HH - 1.0f) * 0.5f, 0.0f), (float)(HH - 1));
        float x0f = floorf(ix), y0f = floorf(iy);
        float wx = ix - x0f, wy = iy - y0f;
        int x0 = (int)x0f, y0 = (int)y0f;
        int x1 = min(x0 + 1, WWW - 1), y1 = min(y0 + 1, HH - 1);
        const unsigned short* base = imgT + (size_t)v * HH * WWW * C2C;
        us4 a = *((const us4*)(base + ((size_t)(y0 * WWW + x0)) * C2C) + l);
        us4 b = *((const us4*)(base + ((size_t)(y0 * WWW + x1)) * C2C) + l);
        us4 c = *((const us4*)(base + ((size_t)(y1 * WWW + x0)) * C2C) + l);
        us4 d = *((const us4*)(base + ((size_t)(y1 * WWW + x1)) * C2C) + l);
        float w00 = (1.0f - wy) * (1.0f - wx), w01 = (1.0f - wy) * wx;
        float w10 = wy * (1.0f - wx), w11 = wy * wx;
        us4 rv;
#pragma unroll
        for (int r = 0; r < 4; r++) {
            float f = b2f(a[r]) * w00 + b2f(b[r]) * w01 + b2f(c[r]) * w10 + b2f(d[r]) * w11;
            rv[r] = f2b(f);
        }
        *(us4*)(dstRow + l * 4) = rv;
    }
    {
        float gx = pts[n * 3 + 0] * 2.0f, gy = pts[n * 3 + 1] * 2.0f, gz = pts[n * 3 + 2] * 2.0f;
        float ix = fminf(fmaxf(((gx + 1.0f) * (float)DDD - 1.0f) * 0.5f, 0.0f), (float)(DDD - 1));
        float iy = fminf(fmaxf(((gy + 1.0f) * (float)DDD - 1.0f) * 0.5f, 0.0f), (float)(DDD - 1));
        float iz = fminf(fmaxf(((gz + 1.0f) * (float)DDD - 1.0f) * 0.5f, 0.0f), (float)(DDD - 1));
        float x0f = floorf(ix), y0f = floorf(iy), z0f = floorf(iz);
        float wx = ix - x0f, wy = iy - y0f, wz = iz - z0f;
        int x0 = (int)x0f, y0 = (int)y0f, z0 = (int)z0f;
        int x1 = min(x0 + 1, DDD - 1), y1 = min(y0 + 1, DDD - 1), z1 = min(z0 + 1, DDD - 1);
        int c = l & 31, zs = l >> 5;
        int zi = zs ? z1 : z0;
        float wzs = zs ? wz : (1.0f - wz);
        const unsigned short* base = volT + (size_t)v * 32768 * C3C;
        float f00 = b2f(base[((size_t)((zi * 32 + y0) * 32 + x0)) * C3C + c]);
        float f01 = b2f(base[((size_t)((zi * 32 + y0) * 32 + x1)) * C3C + c]);
        float f10 = b2f(base[((size_t)((zi * 32 + y1) * 32 + x0)) * C3C + c]);
        float f11 = b2f(base[((size_t)((zi * 32 + y1) * 32 + x1)) * C3C + c]);
        float r = (f00 * (1.0f - wy) * (1.0f - wx) + f01 * (1.0f - wy) * wx +
                   f10 * wy * (1.0f - wx) + f11 * wy * wx) * wzs;
        float other = __shfl_xor(r, 32);
        r += other;
        if (zs == 0) dstRow[C2C + c] = f2b(r);
    }
    if (l < 8) *(us4*)(dstRow + CINC + l * 4) = (us4){0, 0, 0, 0};
}

// ---------------- 128x128 GEMM, double-buffered, 1 raw barrier/K-step, counted drain ----------------
// stage(t+1) issued BEFORE compute(t); vmcnt(0) drain overlapped with the 16 MFMAs.
template <int K2, int M>
__device__ __forceinline__ void gemm128_body(const unsigned short* __restrict__ A,
                                             const unsigned short* __restrict__ B1,
                                             const unsigned short* __restrict__ B2,
                                             const float* __restrict__ bias,
                                             unsigned short* __restrict__ C) {
    constexpr int K1 = CINP;
    constexpr int K = K1 + K2;
    constexpr int nt1 = K1 / 32;
    constexpr int nt = K / 32;
    __shared__ unsigned short Ash[2][128 * 32];
    __shared__ unsigned short Bsh[2][128 * 32];
    int tid = threadIdx.x;
    int w = tid >> 6, l = tid & 63;
    int la = l & 15, lg = l >> 4;
    int wm = w & 1, wn = w >> 1;
    int gx = gridDim.x;
    int nwg = gx * gridDim.y;
    int bid = xcd_swz(blockIdx.y * gx + blockIdx.x, nwg);
    int mBlk = (bid % gx) * 128;
    int nBlk = (bid / gx) * 128;
    int sRow = l >> 2, sCol = (l & 3) * 8;
    int r0 = w * 32 + sRow, r1 = r0 + 16;

    const unsigned short* Ag = A + (size_t)mBlk * K;
    const unsigned short* B1g = B1 + (size_t)nBlk * K1;
    const unsigned short* B2g = (K2 > 0) ? (B2 + (size_t)nBlk * K2) : (const unsigned short*)0;

    fx4 acc[4][4];
#pragma unroll
    for (int mi = 0; mi < 4; mi++)
#pragma unroll
        for (int ni = 0; ni < 4; ni++) acc[mi][ni] = (fx4){0.f, 0.f, 0.f, 0.f};

    auto stage = [&](int t, int nxt) {
        const unsigned short* as = Ag + t * 32 + sCol;
        gl2lds16(as + (size_t)r0 * K, &Ash[nxt][r0 * 32 + sCol]);
        gl2lds16(as + (size_t)r1 * K, &Ash[nxt][r1 * 32 + sCol]);
        const unsigned short* bs;
        size_t ldb;
        if (t < nt1) { bs = B1g + t * 32 + sCol; ldb = (size_t)K1; }
        else         { bs = B2g + (t - nt1) * 32 + sCol; ldb = (size_t)K2; }
        gl2lds16(bs + (size_t)r0 * ldb, &Bsh[nxt][r0 * 32 + sCol]);
        gl2lds16(bs + (size_t)r1 * ldb, &Bsh[nxt][r1 * 32 + sCol]);
    };

    stage(0, 0);
    asm volatile("s_waitcnt vmcnt(0)" ::: "memory");
    __builtin_amdgcn_s_barrier();
    for (int t = 0; t < nt; t++) {
        int cur = t & 1;
        if (t + 1 < nt) stage(t + 1, cur ^ 1);
        bh8 af[4], bfv[4];
#pragma unroll
        for (int mi = 0; mi < 4; mi++) af[mi] = *(const bh8*)&Ash[cur][(wm * 64 + mi * 16 + la) * 32 + lg * 8];
#pragma unroll
        for (int ni = 0; ni < 4; ni++) bfv[ni] = *(const bh8*)&Bsh[cur][(wn * 64 + ni * 16 + la) * 32 + lg * 8];
#pragma unroll
        for (int mi = 0; mi < 4; mi++)
#pragma unroll
            for (int ni = 0; ni < 4; ni++)
                acc[mi][ni] = __builtin_amdgcn_mfma_f32_16x16x32_bf16(af[mi], bfv[ni], acc[mi][ni], 0, 0, 0);
        asm volatile("s_waitcnt lgkmcnt(0)" ::: "memory");
        if (t + 1 < nt) asm volatile("s_waitcnt vmcnt(0)" ::: "memory");
        __builtin_amdgcn_s_barrier();
    }

#pragma unroll
    for (int mi = 0; mi < 4; mi++) {
        int m0 = mBlk + wm * 64 + mi * 16 + lg * 4;
        fx4 bb = *(const fx4*)(bias + m0);
#pragma unroll
        for (int ni = 0; ni < 4; ni++) {
            int n = nBlk + wn * 64 + ni * 16 + la;
            us4 rv;
#pragma unroll
            for (int r = 0; r < 4; r++) {
                float x = acc[mi][ni][r] + bb[r];
                x = (x >= 0.0f) ? x : 0.2f * x;
                rv[r] = f2b(x);
            }
            *(us4*)(C + (size_t)n * M + m0) = rv;
        }
    }
}

__global__ __launch_bounds__(256) void k_g0(const unsigned short* __restrict__ A, const unsigned short* __restrict__ B1,
                                            const float* __restrict__ bias, unsigned short* __restrict__ C) {
    gemm128_body<0, 1024>(A, B1, nullptr, bias, C);
}
__global__ __launch_bounds__(256) void k_g2(const unsigned short* __restrict__ A, const unsigned short* __restrict__ B1,
                                            const unsigned short* __restrict__ B2, const float* __restrict__ bias,
                                            unsigned short* __restrict__ C) {
    gemm128_body<512, 256>(A, B1, B2, bias, C);
}
__global__ __launch_bounds__(256) void k_g3(const unsigned short* __restrict__ A, const unsigned short* __restrict__ B1,
                                            const unsigned short* __restrict__ B2, const float* __restrict__ bias,
                                            unsigned short* __restrict__ C) {
    gemm128_body<256, 128>(A, B1, B2, bias, C);
}

// ---------------- 256x256 4-phase GEMM with TRUE counted vmcnt (T3+T4), L1 ----------------
// Stage of tile t+1 split: B(all) at p0, A-half1 at p1, A-half2 at p2.
// Waits: p1-end vmcnt(6) [drains t's A-half2]; p3-end lgkm(0)+vmcnt(2) [drains t+1's B+A1].
// Uniform per-thread issue order => after barrier a PREFIX of the tile is valid.
__global__ __launch_bounds__(512) void k_g1(const unsigned short* __restrict__ A,
                                            const unsigned short* __restrict__ B1,
                                            const unsigned short* __restrict__ B2,
                                            const float* __restrict__ bias,
                                            unsigned short* __restrict__ C) {
    constexpr int Kp = 1344;
    constexpr int K2 = 1024;
    constexpr int M = 512;
    constexpr int nt = Kp >> 6;
    __shared__ unsigned short As[2][256 * 64];
    __shared__ unsigned short Bs[2][256 * 64];
    int tid = threadIdx.x;
    int w = tid >> 6, l = tid & 63;
    int la = l & 15, lg = l >> 4;
    int wm = w >> 2, wn = w & 3;
    int gx = gridDim.x;
    int nwg = gx * gridDim.y;
    int bid = xcd_swz(blockIdx.y * gx + blockIdx.x, nwg);
    int mBlk = (bid % gx) * 256;
    int nBlk = (bid / gx) * 256;

    const unsigned short* Ag = A + (size_t)mBlk * Kp;

    fx4 acc[8][4];
#pragma unroll
    for (int mi = 0; mi < 8; mi++)
#pragma unroll
        for (int ni = 0; ni < 4; ni++) acc[mi][ni] = (fx4){0.f, 0.f, 0.f, 0.f};

    auto stageB = [&](int t, int nxt) {  // 4 loads/thread: all 256 B rows
        const unsigned short* bsrc;
        size_t ldb;
        int kc;
        if (t < 5) { bsrc = B1; ldb = CINP; kc = t * 64; }
        else       { bsrc = B2; ldb = (size_t)K2; kc = (t - 5) * 64; }
        bsrc += (size_t)nBlk * ldb + kc;
#pragma unroll
        for (int h = 0; h < 2; h++)
#pragma unroll
            for (int j = 0; j < 2; j++) {
                int idx = j * 512 + tid;
                int r = (h << 7) + (idx >> 3);
                int c = (idx & 7) ^ (r & 7);
                gl2lds16(bsrc + (size_t)r * ldb + c * 8, &Bs[nxt][(h << 13) + idx * 8]);
            }
    };
    auto stageA1 = [&](int t, int nxt) {  // 2 loads: A rows 0-63 & 128-191 (qm=0 data)
        const unsigned short* asrc = Ag + t * 64;
#pragma unroll
        for (int h = 0; h < 2; h++) {
            int idx = tid;
            int r = (h << 7) + (idx >> 3);
            int c = (idx & 7) ^ (r & 7);
            gl2lds16(asrc + (size_t)r * Kp + c * 8, &As[nxt][(h << 13) + idx * 8]);
        }
    };
    auto stageA2 = [&](int t, int nxt) {  // 2 loads: A rows 64-127 & 192-255 (qm=1 data)
        const unsigned short* asrc = Ag + t * 64;
#pragma unroll
        for (int h = 0; h < 2; h++) {
            int idx = 512 + tid;
            int r = (h << 7) + (idx >> 3);
            int c = (idx & 7) ^ (r & 7);
            gl2lds16(asrc + (size_t)r * Kp + c * 8, &As[nxt][(h << 13) + idx * 8]);
        }
    };

    stageB(0, 0);
    stageA1(0, 0);
    stageA2(0, 0);
    asm volatile("s_waitcnt vmcnt(0)" ::: "memory");
    __builtin_amdgcn_s_barrier();

    for (int t = 0; t < nt; t++) {
        int cur = t & 1;
        const unsigned short* Ab = &As[cur][0];
        const unsigned short* Bb = &Bs[cur][0];
        bh8 afr[4][2];
#pragma unroll
        for (int p = 0; p < 4; p++) {
            int qm = p >> 1, qn = p & 1;
            if (qn == 0) {
#pragma unroll
                for (int m2 = 0; m2 < 4; m2++)
#pragma unroll
                    for (int s = 0; s < 2; s++) {
                        int row = wm * 128 + (qm * 4 + m2) * 16 + la;
                        int c = (s * 4 + lg) ^ (row & 7);
                        afr[m2][s] = *(const bh8*)&Ab[row * 64 + c * 8];
                    }
            }
            bh8 bfr[2][2];
#pragma unroll
            for (int n2 = 0; n2 < 2; n2++)
#pragma unroll
                for (int s = 0; s < 2; s++) {
                    int row = wn * 64 + (qn * 2 + n2) * 16 + la;
                    int c = (s * 4 + lg) ^ (row & 7);
                    bfr[n2][s] = *(const bh8*)&Bb[row * 64 + c * 8];
                }
            if (p == 0 && t + 1 < nt) stageB(t + 1, cur ^ 1);
            if (p == 1 && t + 1 < nt) stageA1(t + 1, cur ^ 1);
            if (p == 2 && t + 1 < nt) stageA2(t + 1, cur ^ 1);
            __builtin_amdgcn_s_barrier();
            __builtin_amdgcn_s_setprio(1);
#pragma unroll
            for (int m2 = 0; m2 < 4; m2++)
#pragma unroll
                for (int n2 = 0; n2 < 2; n2++)
#pragma unroll
                    for (int s = 0; s < 2; s++)
                        acc[qm * 4 + m2][qn * 2 + n2] = __builtin_amdgcn_mfma_f32_16x16x32_bf16(
                            afr[m2][s], bfr[n2][s], acc[qm * 4 + m2][qn * 2 + n2], 0, 0, 0);
            __builtin_amdgcn_s_setprio(0);
            if (p == 1) {
                if (t + 1 < nt) asm volatile("s_waitcnt vmcnt(6)" ::: "memory");
                else            asm volatile("s_waitcnt vmcnt(0)" ::: "memory");
            }
            if (p == 3) {
                asm volatile("s_waitcnt lgkmcnt(0)" ::: "memory");
                if (t + 1 < nt) asm volatile("s_waitcnt vmcnt(2)" ::: "memory");
            }
            __builtin_amdgcn_s_barrier();
        }
    }

#pragma unroll
    for (int mi = 0; mi < 8; mi++) {
        int m0 = mBlk + wm * 128 + mi * 16 + lg * 4;
        fx4 bb = *(const fx4*)(bias + m0);
#pragma unroll
        for (int ni = 0; ni < 4; ni++) {
            int n = nBlk + wn * 64 + ni * 16 + la;
            us4 rv;
#pragma unroll
            for (int r = 0; r < 4; r++) {
                float x = acc[mi][ni][r] + bb[r];
                x = (x >= 0.0f) ? x : 0.2f * x;
                rv[r] = f2b(x);
            }
            *(us4*)(C + (size_t)n * M + m0) = rv;
        }
    }
}

// ---------------- head: 16 lanes per point, coalesced rows, shuffle reduce ----------------
__global__ __launch_bounds__(256) void k_head(const unsigned short* __restrict__ o3, const float* __restrict__ W4,
                       const float* __restrict__ b4, const int* __restrict__ mn_p,
                       float* __restrict__ out, int n0, int Nk, int level) {
    int wv = threadIdx.x >> 6, l = threadIdx.x & 63;
    int sub = l >> 4, cl = l & 15;
    int i = blockIdx.x * 16 + wv * 4 + sub;
    if (i >= Nk) return;
    int mn = *mn_p;
    if (mn > NV) mn = NV;
    if (mn < 1) mn = 1;
    fx4 w0 = *(const fx4*)(W4 + cl * 8);
    fx4 w1 = *(const fx4*)(W4 + cl * 8 + 4);
    float s = 0.0f;
    for (int v = 0; v < mn; v++) {
        bh8 x = *(const bh8*)(o3 + (size_t)(v * Nk + i) * 128 + cl * 8);
#pragma unroll
        for (int r = 0; r < 4; r++) s += w0[r] * b2f((unsigned short)x[r]);
#pragma unroll
        for (int r = 0; r < 4; r++) s += w1[r] * b2f((unsigned short)x[4 + r]);
    }
#pragma unroll
    for (int m = 1; m < 16; m <<= 1) s += __shfl_xor(s, m);
    if (cl == 0) {
        s = s / (float)mn + b4[0];
        out[(size_t)level * NPTS + n0 + i] = 1.0f / (1.0f + expf(-s));
    }
}

extern "C" void kernel_launch(void* const* d_in, const int* in_sizes, int n_in,
                              void* d_out, int out_size, void* d_ws, size_t ws_size,
                              hipStream_t stream) {
    const float* pts = (const float*)d_in[0];
    const float* proj = (const float*)d_in[1];
    const float* img[2] = {(const float*)d_in[2], (const float*)d_in[3]};
    const float* vol[2] = {(const float*)d_in[4], (const float*)d_in[5]};
    const float* Wf[4] = {(const float*)d_in[6], (const float*)d_in[8], (const float*)d_in[10], (const float*)d_in[12]};
    const float* bf[4] = {(const float*)d_in[7], (const float*)d_in[9], (const float*)d_in[11], (const float*)d_in[13]};
    const float* W4 = (const float*)d_in[14];
    const float* b4 = (const float*)d_in[15];
    const int* mn = (const int*)d_in[16];
    float* out = (float*)d_out;

    const int Kp[4] = {320, 1344, 832, 576};
    const int Msz[4] = {1024, 512, 256, 128};

    char* ws = (char*)d_ws;
    size_t off = 0;
    auto alloc = [&](size_t bytes) -> char* {
        char* p = ws + off;
        off = (off + bytes + 255) & ~(size_t)255;
        return p;
    };

    const size_t imgStride = (size_t)NV * HH * WWW * C2C;
    const size_t volStride = (size_t)NV * 32768 * C3C;

    unsigned short* Wb[4];
    for (int i = 0; i < 4; i++) Wb[i] = (unsigned short*)alloc((size_t)Msz[i] * Kp[i] * 2);
    unsigned short* imgT = (unsigned short*)alloc(2 * imgStride * 2);
    unsigned short* volT = (unsigned short*)alloc(2 * volStride * 2);
    size_t fixed = off;

    // per-point bytes: 3 views * 2B * (320 + 1024 + 512); o2/o3 alias into o0's buffer
    const size_t perPt = (size_t)NV * 2 * (CINP + 1024 + 512);
    int Nk = NPTS;
    if (fixed + (size_t)Nk * perPt + 4096 > ws_size) {
        size_t avail = (ws_size > fixed + 4096) ? (ws_size - fixed - 4096) : 0;
        long nk = (long)(avail / perPt);
        nk = (nk / 512) * 512;
        if (nk < 512) nk = 512;
        if (nk > NPTS) nk = NPTS;
        Nk = (int)nk;
    }
    unsigned short* ptT = (unsigned short*)alloc((size_t)NV * Nk * CINP * 2);
    unsigned short* o0 = (unsigned short*)alloc((size_t)NV * Nk * 1024 * 2);
    unsigned short* o1 = (unsigned short*)alloc((size_t)NV * Nk * 512 * 2);
    unsigned short* o2 = o0;                                   // alias: o0 dead once g2 runs
    unsigned short* o3 = o0 + (size_t)NV * Nk * 256;           // alias: after o2 region

    k_wpad4<<<dim3(2688, 4), 256, 0, stream>>>(Wf[0], Wf[1], Wf[2], Wf[3], Wb[0], Wb[1], Wb[2], Wb[3]);
    k_timg<<<dim3(NV * HH, WWW / 64, 8), 256, 0, stream>>>(img[0], img[1], imgT, imgStride);
    k_tvol<<<dim3(NV, 32768 / 256, 2), 256, 0, stream>>>(vol[0], vol[1], volT, volStride);

    for (int lvl = 0; lvl < 2; lvl++) {
        for (int n0 = 0; n0 < NPTS; n0 += Nk) {
            int nk = NPTS - n0 < Nk ? NPTS - n0 : Nk;
            int NC = NV * nk;
            k_sample<<<dim3(nk / 4, NV), 256, 0, stream>>>(pts, proj, imgT + lvl * imgStride,
                                                           volT + lvl * volStride, ptT, n0, nk);
            k_g0<<<dim3(1024 / 128, NC / 128), 256, 0, stream>>>(Wb[0], ptT, bf[0], o0);
            k_g1<<<dim3(512 / 256, NC / 256), 512, 0, stream>>>(Wb[1], ptT, o0, bf[1], o1);
            k_g2<<<dim3(256 / 128, NC / 128), 256, 0, stream>>>(Wb[2], ptT, o1, bf[2], o2);
            k_g3<<<dim3(128 / 128, NC / 128), 256, 0, stream>>>(Wb[3], ptT, o2, bf[3], o3);
            k_head<<<(nk + 15) / 16, 256, 0, stream>>>(o3, W4, b4, mn, out, n0, nk, lvl);
        }
    }
}

// Round 10
// 1059.182 us; speedup vs baseline: 1.1312x; 1.0057x over previous
//
#include <hip/hip_runtime.h>
#include <hip/hip_bf16.h>

#define NV 3
#define NPTS 32768
#define C2C 256
#define C3C 32
#define CINC 288
#define CINP 320
#define HH 128
#define WWW 128
#define DDD 32

typedef short bh8 __attribute__((ext_vector_type(8)));
typedef float fx4 __attribute__((ext_vector_type(4)));
typedef unsigned short us4 __attribute__((ext_vector_type(4)));

__device__ __forceinline__ float b2f(unsigned short u) {
    unsigned int x = ((unsigned int)u) << 16;
    return __uint_as_float(x);
}
__device__ __forceinline__ unsigned short f2b(float f) {
    unsigned int x = __float_as_uint(f);
    unsigned int r = (x + 0x7FFFu + ((x >> 16) & 1u)) >> 16;
    return (unsigned short)r;
}

__device__ __forceinline__ void gl2lds16(const unsigned short* g, unsigned short* l) {
    __builtin_amdgcn_global_load_lds(
        (const __attribute__((address_space(1))) unsigned int*)g,
        (__attribute__((address_space(3))) unsigned int*)l, 16, 0, 0);
}

// bijective XCD-aware block swizzle (m204)
__device__ __forceinline__ int xcd_swz(int orig, int nwg) {
    int xcd = orig & 7;
    int q = nwg >> 3, r = nwg & 7;
    int base = (xcd < r) ? xcd * (q + 1) : r * (q + 1) + (xcd - r) * q;
    return base + (orig >> 3);
}

// ---------------- all 4 weights f32 -> bf16 padded, one dispatch ----------------
__global__ void k_wpad4(const float* __restrict__ s0, const float* __restrict__ s1,
                        const float* __restrict__ s2, const float* __restrict__ s3,
                        unsigned short* __restrict__ d0, unsigned short* __restrict__ d1,
                        unsigned short* __restrict__ d2, unsigned short* __restrict__ d3) {
    const int Ms[4] = {1024, 512, 256, 128};
    const int Kps[4] = {320, 1344, 832, 576};
    int i = blockIdx.y;
    int M = Ms[i], Kp = Kps[i];
    int idx = blockIdx.x * 256 + threadIdx.x;
    if (idx >= M * Kp) return;
    const float* src = (i == 0) ? s0 : (i == 1) ? s1 : (i == 2) ? s2 : s3;
    unsigned short* dst = (i == 0) ? d0 : (i == 1) ? d1 : (i == 2) ? d2 : d3;
    int m = idx / Kp, k = idx - m * Kp;
    int Ksrc = Kp - 32;
    float v;
    if (k < CINC) v = src[(size_t)m * Ksrc + k];
    else if (k < CINP) v = 0.0f;
    else v = src[(size_t)m * Ksrc + (k - 32)];
    dst[idx] = f2b(v);
}

// ---------------- img (V,C2,H,W) f32 -> (V,H,W,C2) bf16, both levels ----------------
__global__ void k_timg(const float* __restrict__ in0, const float* __restrict__ in1,
                       unsigned short* __restrict__ out, size_t lvlStride) {
    int lvl = blockIdx.z >> 2, cb = blockIdx.z & 3;
    const float* in = lvl ? in1 : in0;
    int v = blockIdx.x >> 7, y = blockIdx.x & 127;
    int x0 = blockIdx.y << 6, c0 = cb << 6;
    __shared__ float t[64][65];
    int tx = threadIdx.x & 63, tg = threadIdx.x >> 6;
    const float* src = in + (((size_t)(v * C2C + c0) * HH + y) * WWW + x0);
#pragma unroll
    for (int i = 0; i < 16; i++) {
        int cl = tg * 16 + i;
        t[cl][tx] = src[(size_t)cl * (HH * WWW) + tx];
    }
    __syncthreads();
    unsigned short* dst = out + lvl * lvlStride + ((size_t)(v * HH + y) * WWW + x0) * C2C + c0;
#pragma unroll
    for (int i = 0; i < 16; i++) {
        int xl = tg * 16 + i;
        dst[(size_t)xl * C2C + tx] = f2b(t[tx][xl]);
    }
}

// ---------------- vol (V,C3,32,32,32) f32 -> (V,32768,C3) bf16, both levels ----------------
__global__ void k_tvol(const float* __restrict__ in0, const float* __restrict__ in1,
                       unsigned short* __restrict__ out, size_t lvlStride) {
    int lvl = blockIdx.z;
    const float* in = lvl ? in1 : in0;
    int v = blockIdx.x;
    int s0 = blockIdx.y << 8;
    __shared__ float t[32][257];
    int tid = threadIdx.x;
    const float* src = in + (size_t)v * C3C * 32768 + s0;
#pragma unroll
    for (int c = 0; c < 32; c++) t[c][tid] = src[(size_t)c * 32768 + tid];
    __syncthreads();
    unsigned short* dst = out + lvl * lvlStride + ((size_t)v * 32768 + s0) * C3C;
    int c = tid & 31, sb = tid >> 5;
#pragma unroll
    for (int j = 0; j < 32; j++) {
        int sl = j * 8 + sb;
        dst[(size_t)sl * C3C + c] = f2b(t[c][sl]);
    }
}

// ---------------- sampler body: wave per (point,view) ----------------
__device__ __forceinline__ void sample_body(const float* __restrict__ pts, const float* __restrict__ proj,
                         const unsigned short* __restrict__ imgT, const unsigned short* __restrict__ volT,
                         unsigned short* __restrict__ ptT, int n0, int Nk) {
    int w = threadIdx.x >> 6, l = threadIdx.x & 63;
    int i = blockIdx.x * 4 + w;
    int v = blockIdx.y;
    int n = n0 + i;
    unsigned short* dstRow = ptT + (size_t)(v * Nk + i) * CINP;

    {
        float gx = proj[n * 2 + 0], gy = proj[n * 2 + 1];
        float ix = fminf(fmaxf(((gx + 1.0f) * (float)WWW - 1.0f) * 0.5f, 0.0f), (float)(WWW - 1));
        float iy = fminf(fmaxf(((gy + 1.0f) * (float)HH - 1.0f) * 0.5f, 0.0f), (float)(HH - 1));
        float x0f = floorf(ix), y0f = floorf(iy);
        float wx = ix - x0f, wy = iy - y0f;
        int x0 = (int)x0f, y0 = (int)y0f;
        int x1 = min(x0 + 1, WWW - 1), y1 = min(y0 + 1, HH - 1);
        const unsigned short* base = imgT + (size_t)v * HH * WWW * C2C;
        us4 a = *((const us4*)(base + ((size_t)(y0 * WWW + x0)) * C2C) + l);
        us4 b = *((const us4*)(base + ((size_t)(y0 * WWW + x1)) * C2C) + l);
        us4 c = *((const us4*)(base + ((size_t)(y1 * WWW + x0)) * C2C) + l);
        us4 d = *((const us4*)(base + ((size_t)(y1 * WWW + x1)) * C2C) + l);
        float w00 = (1.0f - wy) * (1.0f - wx), w01 = (1.0f - wy) * wx;
        float w10 = wy * (1.0f - wx), w11 = wy * wx;
        us4 rv;
#pragma unroll
        for (int r = 0; r < 4; r++) {
            float f = b2f(a[r]) * w00 + b2f(b[r]) * w01 + b2f(c[r]) * w10 + b2f(d[r]) * w11;
            rv[r] = f2b(f);
        }
        *(us4*)(dstRow + l * 4) = rv;
    }
    {
        float gx = pts[n * 3 + 0] * 2.0f, gy = pts[n * 3 + 1] * 2.0f, gz = pts[n * 3 + 2] * 2.0f;
        float ix = fminf(fmaxf(((gx + 1.0f) * (float)DDD - 1.0f) * 0.5f, 0.0f), (float)(DDD - 1));
        float iy = fminf(fmaxf(((gy + 1.0f) * (float)DDD - 1.0f) * 0.5f, 0.0f), (float)(DDD - 1));
        float iz = fminf(fmaxf(((gz + 1.0f) * (float)DDD - 1.0f) * 0.5f, 0.0f), (float)(DDD - 1));
        float x0f = floorf(ix), y0f = floorf(iy), z0f = floorf(iz);
        float wx = ix - x0f, wy = iy - y0f, wz = iz - z0f;
        int x0 = (int)x0f, y0 = (int)y0f, z0 = (int)z0f;
        int x1 = min(x0 + 1, DDD - 1), y1 = min(y0 + 1, DDD - 1), z1 = min(z0 + 1, DDD - 1);
        int c = l & 31, zs = l >> 5;
        int zi = zs ? z1 : z0;
        float wzs = zs ? wz : (1.0f - wz);
        const unsigned short* base = volT + (size_t)v * 32768 * C3C;
        float f00 = b2f(base[((size_t)((zi * 32 + y0) * 32 + x0)) * C3C + c]);
        float f01 = b2f(base[((size_t)((zi * 32 + y0) * 32 + x1)) * C3C + c]);
        float f10 = b2f(base[((size_t)((zi * 32 + y1) * 32 + x0)) * C3C + c]);
        float f11 = b2f(base[((size_t)((zi * 32 + y1) * 32 + x1)) * C3C + c]);
        float r = (f00 * (1.0f - wy) * (1.0f - wx) + f01 * (1.0f - wy) * wx +
                   f10 * wy * (1.0f - wx) + f11 * wy * wx) * wzs;
        float other = __shfl_xor(r, 32);
        r += other;
        if (zs == 0) dstRow[C2C + c] = f2b(r);
    }
    if (l < 8) *(us4*)(dstRow + CINC + l * 4) = (us4){0, 0, 0, 0};
}

__global__ __launch_bounds__(256) void k_sampleL0(const float* p, const float* pr, const unsigned short* im,
                                                  const unsigned short* vo, unsigned short* pt, int n0, int Nk) {
    sample_body(p, pr, im, vo, pt, n0, Nk);
}
__global__ __launch_bounds__(256) void k_sampleL1(const float* p, const float* pr, const unsigned short* im,
                                                  const unsigned short* vo, unsigned short* pt, int n0, int Nk) {
    sample_body(p, pr, im, vo, pt, n0, Nk);
}

// ---------------- 128x128 GEMM, TRIPLE-buffered, counted vmcnt(4), 1 barrier/K-step ----------------
// stage(t+2) issued at iter top; end-of-iter vmcnt(4) leaves only tile t+2 in flight (counted, T4).
template <int K2, int M>
__device__ __forceinline__ void gemm128_body(const unsigned short* __restrict__ A,
                                             const unsigned short* __restrict__ B1,
                                             const unsigned short* __restrict__ B2,
                                             const float* __restrict__ bias,
                                             unsigned short* __restrict__ C) {
    constexpr int K1 = CINP;
    constexpr int K = K1 + K2;
    constexpr int nt1 = K1 / 32;
    constexpr int nt = K / 32;
    __shared__ unsigned short Ash[3][128 * 32];
    __shared__ unsigned short Bsh[3][128 * 32];
    int tid = threadIdx.x;
    int w = tid >> 6, l = tid & 63;
    int la = l & 15, lg = l >> 4;
    int wm = w & 1, wn = w >> 1;
    int gx = gridDim.x;
    int nwg = gx * gridDim.y;
    int bid = xcd_swz(blockIdx.y * gx + blockIdx.x, nwg);
    int mBlk = (bid % gx) * 128;
    int nBlk = (bid / gx) * 128;
    int sRow = l >> 2, sCol = (l & 3) * 8;
    int r0 = w * 32 + sRow, r1 = r0 + 16;

    const unsigned short* Ag = A + (size_t)mBlk * K;
    const unsigned short* B1g = B1 + (size_t)nBlk * K1;
    const unsigned short* B2g = (K2 > 0) ? (B2 + (size_t)nBlk * K2) : (const unsigned short*)0;

    fx4 acc[4][4];
#pragma unroll
    for (int mi = 0; mi < 4; mi++)
#pragma unroll
        for (int ni = 0; ni < 4; ni++) acc[mi][ni] = (fx4){0.f, 0.f, 0.f, 0.f};

    auto stage = [&](int t, int b) {
        const unsigned short* as = Ag + t * 32 + sCol;
        gl2lds16(as + (size_t)r0 * K, &Ash[b][r0 * 32 + sCol]);
        gl2lds16(as + (size_t)r1 * K, &Ash[b][r1 * 32 + sCol]);
        const unsigned short* bs;
        size_t ldb;
        if (t < nt1) { bs = B1g + t * 32 + sCol; ldb = (size_t)K1; }
        else         { bs = B2g + (t - nt1) * 32 + sCol; ldb = (size_t)K2; }
        gl2lds16(bs + (size_t)r0 * ldb, &Bsh[b][r0 * 32 + sCol]);
        gl2lds16(bs + (size_t)r1 * ldb, &Bsh[b][r1 * 32 + sCol]);
    };

    stage(0, 0);
    if (nt > 1) stage(1, 1);
    asm volatile("s_waitcnt vmcnt(4)" ::: "memory");  // tile 0 landed (tile 1 may fly)
    __builtin_amdgcn_s_barrier();
    int cur = 0, nxt2 = 2;
    for (int t = 0; t < nt; t++) {
        if (t + 2 < nt) stage(t + 2, nxt2);
        bh8 af[4], bfv[4];
#pragma unroll
        for (int mi = 0; mi < 4; mi++) af[mi] = *(const bh8*)&Ash[cur][(wm * 64 + mi * 16 + la) * 32 + lg * 8];
#pragma unroll
        for (int ni = 0; ni < 4; ni++) bfv[ni] = *(const bh8*)&Bsh[cur][(wn * 64 + ni * 16 + la) * 32 + lg * 8];
#pragma unroll
        for (int mi = 0; mi < 4; mi++)
#pragma unroll
            for (int ni = 0; ni < 4; ni++)
                acc[mi][ni] = __builtin_amdgcn_mfma_f32_16x16x32_bf16(af[mi], bfv[ni], acc[mi][ni], 0, 0, 0);
        asm volatile("s_waitcnt lgkmcnt(0)" ::: "memory");
        if (t + 2 < nt)      asm volatile("s_waitcnt vmcnt(4)" ::: "memory");  // t+1 landed
        else if (t + 1 < nt) asm volatile("s_waitcnt vmcnt(0)" ::: "memory");
        __builtin_amdgcn_s_barrier();
        cur = (cur == 2) ? 0 : cur + 1;
        nxt2 = (nxt2 == 2) ? 0 : nxt2 + 1;
    }

#pragma unroll
    for (int mi = 0; mi < 4; mi++) {
        int m0 = mBlk + wm * 64 + mi * 16 + lg * 4;
        fx4 bb = *(const fx4*)(bias + m0);
#pragma unroll
        for (int ni = 0; ni < 4; ni++) {
            int n = nBlk + wn * 64 + ni * 16 + la;
            us4 rv;
#pragma unroll
            for (int r = 0; r < 4; r++) {
                float x = acc[mi][ni][r] + bb[r];
                x = (x >= 0.0f) ? x : 0.2f * x;
                rv[r] = f2b(x);
            }
            *(us4*)(C + (size_t)n * M + m0) = rv;
        }
    }
}

__global__ __launch_bounds__(256) void k_g0L0(const unsigned short* A, const unsigned short* B1,
                                              const float* b, unsigned short* C) { gemm128_body<0, 1024>(A, B1, nullptr, b, C); }
__global__ __launch_bounds__(256) void k_g0L1(const unsigned short* A, const unsigned short* B1,
                                              const float* b, unsigned short* C) { gemm128_body<0, 1024>(A, B1, nullptr, b, C); }
__global__ __launch_bounds__(256) void k_g2L0(const unsigned short* A, const unsigned short* B1, const unsigned short* B2,
                                              const float* b, unsigned short* C) { gemm128_body<512, 256>(A, B1, B2, b, C); }
__global__ __launch_bounds__(256) void k_g2L1(const unsigned short* A, const unsigned short* B1, const unsigned short* B2,
                                              const float* b, unsigned short* C) { gemm128_body<512, 256>(A, B1, B2, b, C); }
__global__ __launch_bounds__(256) void k_g3L0(const unsigned short* A, const unsigned short* B1, const unsigned short* B2,
                                              const float* b, unsigned short* C) { gemm128_body<256, 128>(A, B1, B2, b, C); }
__global__ __launch_bounds__(256) void k_g3L1(const unsigned short* A, const unsigned short* B1, const unsigned short* B2,
                                              const float* b, unsigned short* C) { gemm128_body<256, 128>(A, B1, B2, b, C); }

// ---------------- 256x256 4-phase GEMM with counted vmcnt (T3+T4+T5), L1 layer ----------------
__device__ __forceinline__ void g1_body(const unsigned short* __restrict__ A,
                                        const unsigned short* __restrict__ B1,
                                        const unsigned short* __restrict__ B2,
                                        const float* __restrict__ bias,
                                        unsigned short* __restrict__ C) {
    constexpr int Kp = 1344;
    constexpr int K2 = 1024;
    constexpr int M = 512;
    constexpr int nt = Kp >> 6;
    __shared__ unsigned short As[2][256 * 64];
    __shared__ unsigned short Bs[2][256 * 64];
    int tid = threadIdx.x;
    int w = tid >> 6, l = tid & 63;
    int la = l & 15, lg = l >> 4;
    int wm = w >> 2, wn = w & 3;
    int gx = gridDim.x;
    int nwg = gx * gridDim.y;
    int bid = xcd_swz(blockIdx.y * gx + blockIdx.x, nwg);
    int mBlk = (bid % gx) * 256;
    int nBlk = (bid / gx) * 256;

    const unsigned short* Ag = A + (size_t)mBlk * Kp;

    fx4 acc[8][4];
#pragma unroll
    for (int mi = 0; mi < 8; mi++)
#pragma unroll
        for (int ni = 0; ni < 4; ni++) acc[mi][ni] = (fx4){0.f, 0.f, 0.f, 0.f};

    auto stageB = [&](int t, int nxt) {
        const unsigned short* bsrc;
        size_t ldb;
        int kc;
        if (t < 5) { bsrc = B1; ldb = CINP; kc = t * 64; }
        else       { bsrc = B2; ldb = (size_t)K2; kc = (t - 5) * 64; }
        bsrc += (size_t)nBlk * ldb + kc;
#pragma unroll
        for (int h = 0; h < 2; h++)
#pragma unroll
            for (int j = 0; j < 2; j++) {
                int idx = j * 512 + tid;
                int r = (h << 7) + (idx >> 3);
                int c = (idx & 7) ^ (r & 7);
                gl2lds16(bsrc + (size_t)r * ldb + c * 8, &Bs[nxt][(h << 13) + idx * 8]);
            }
    };
    auto stageA1 = [&](int t, int nxt) {
        const unsigned short* asrc = Ag + t * 64;
#pragma unroll
        for (int h = 0; h < 2; h++) {
            int idx = tid;
            int r = (h << 7) + (idx >> 3);
            int c = (idx & 7) ^ (r & 7);
            gl2lds16(asrc + (size_t)r * Kp + c * 8, &As[nxt][(h << 13) + idx * 8]);
        }
    };
    auto stageA2 = [&](int t, int nxt) {
        const unsigned short* asrc = Ag + t * 64;
#pragma unroll
        for (int h = 0; h < 2; h++) {
            int idx = 512 + tid;
            int r = (h << 7) + (idx >> 3);
            int c = (idx & 7) ^ (r & 7);
            gl2lds16(asrc + (size_t)r * Kp + c * 8, &As[nxt][(h << 13) + idx * 8]);
        }
    };

    stageB(0, 0);
    stageA1(0, 0);
    stageA2(0, 0);
    asm volatile("s_waitcnt vmcnt(0)" ::: "memory");
    __builtin_amdgcn_s_barrier();

    for (int t = 0; t < nt; t++) {
        int cur = t & 1;
        const unsigned short* Ab = &As[cur][0];
        const unsigned short* Bb = &Bs[cur][0];
        bh8 afr[4][2];
#pragma unroll
        for (int p = 0; p < 4; p++) {
            int qm = p >> 1, qn = p & 1;
            if (qn == 0) {
#pragma unroll
                for (int m2 = 0; m2 < 4; m2++)
#pragma unroll
                    for (int s = 0; s < 2; s++) {
                        int row = wm * 128 + (qm * 4 + m2) * 16 + la;
                        int c = (s * 4 + lg) ^ (row & 7);
                        afr[m2][s] = *(const bh8*)&Ab[row * 64 + c * 8];
                    }
            }
            bh8 bfr[2][2];
#pragma unroll
            for (int n2 = 0; n2 < 2; n2++)
#pragma unroll
                for (int s = 0; s < 2; s++) {
                    int row = wn * 64 + (qn * 2 + n2) * 16 + la;
                    int c = (s * 4 + lg) ^ (row & 7);
                    bfr[n2][s] = *(const bh8*)&Bb[row * 64 + c * 8];
                }
            if (p == 0 && t + 1 < nt) stageB(t + 1, cur ^ 1);
            if (p == 1 && t + 1 < nt) stageA1(t + 1, cur ^ 1);
            if (p == 2 && t + 1 < nt) stageA2(t + 1, cur ^ 1);
            __builtin_amdgcn_s_barrier();
            __builtin_amdgcn_s_setprio(1);
#pragma unroll
            for (int m2 = 0; m2 < 4; m2++)
#pragma unroll
                for (int n2 = 0; n2 < 2; n2++)
#pragma unroll
                    for (int s = 0; s < 2; s++)
                        acc[qm * 4 + m2][qn * 2 + n2] = __builtin_amdgcn_mfma_f32_16x16x32_bf16(
                            afr[m2][s], bfr[n2][s], acc[qm * 4 + m2][qn * 2 + n2], 0, 0, 0);
            __builtin_amdgcn_s_setprio(0);
            if (p == 1) {
                if (t + 1 < nt) asm volatile("s_waitcnt vmcnt(6)" ::: "memory");
                else            asm volatile("s_waitcnt vmcnt(0)" ::: "memory");
            }
            if (p == 3) {
                asm volatile("s_waitcnt lgkmcnt(0)" ::: "memory");
                if (t + 1 < nt) asm volatile("s_waitcnt vmcnt(2)" ::: "memory");
            }
            __builtin_amdgcn_s_barrier();
        }
    }

#pragma unroll
    for (int mi = 0; mi < 8; mi++) {
        int m0 = mBlk + wm * 128 + mi * 16 + lg * 4;
        fx4 bb = *(const fx4*)(bias + m0);
#pragma unroll
        for (int ni = 0; ni < 4; ni++) {
            int n = nBlk + wn * 64 + ni * 16 + la;
            us4 rv;
#pragma unroll
            for (int r = 0; r < 4; r++) {
                float x = acc[mi][ni][r] + bb[r];
                x = (x >= 0.0f) ? x : 0.2f * x;
                rv[r] = f2b(x);
            }
            *(us4*)(C + (size_t)n * M + m0) = rv;
        }
    }
}

__global__ __launch_bounds__(512) void k_g1L0(const unsigned short* A, const unsigned short* B1, const unsigned short* B2,
                                              const float* b, unsigned short* C) { g1_body(A, B1, B2, b, C); }
__global__ __launch_bounds__(512) void k_g1L1(const unsigned short* A, const unsigned short* B1, const unsigned short* B2,
                                              const float* b, unsigned short* C) { g1_body(A, B1, B2, b, C); }

// ---------------- head: 16 lanes per point, coalesced rows, shuffle reduce ----------------
__device__ __forceinline__ void head_body(const unsigned short* __restrict__ o3, const float* __restrict__ W4,
                       const float* __restrict__ b4, const int* __restrict__ mn_p,
                       float* __restrict__ out, int n0, int Nk, int level) {
    int wv = threadIdx.x >> 6, l = threadIdx.x & 63;
    int sub = l >> 4, cl = l & 15;
    int i = blockIdx.x * 16 + wv * 4 + sub;
    if (i >= Nk) return;
    int mn = *mn_p;
    if (mn > NV) mn = NV;
    if (mn < 1) mn = 1;
    fx4 w0 = *(const fx4*)(W4 + cl * 8);
    fx4 w1 = *(const fx4*)(W4 + cl * 8 + 4);
    float s = 0.0f;
    for (int v = 0; v < mn; v++) {
        bh8 x = *(const bh8*)(o3 + (size_t)(v * Nk + i) * 128 + cl * 8);
#pragma unroll
        for (int r = 0; r < 4; r++) s += w0[r] * b2f((unsigned short)x[r]);
#pragma unroll
        for (int r = 0; r < 4; r++) s += w1[r] * b2f((unsigned short)x[4 + r]);
    }
#pragma unroll
    for (int m = 1; m < 16; m <<= 1) s += __shfl_xor(s, m);
    if (cl == 0) {
        s = s / (float)mn + b4[0];
        out[(size_t)level * NPTS + n0 + i] = 1.0f / (1.0f + expf(-s));
    }
}

__global__ __launch_bounds__(256) void k_headL0(const unsigned short* o3, const float* W4, const float* b4,
                                                const int* mn, float* out, int n0, int Nk) {
    head_body(o3, W4, b4, mn, out, n0, Nk, 0);
}
__global__ __launch_bounds__(256) void k_headL1(const unsigned short* o3, const float* W4, const float* b4,
                                                const int* mn, float* out, int n0, int Nk) {
    head_body(o3, W4, b4, mn, out, n0, Nk, 1);
}

extern "C" void kernel_launch(void* const* d_in, const int* in_sizes, int n_in,
                              void* d_out, int out_size, void* d_ws, size_t ws_size,
                              hipStream_t stream) {
    const float* pts = (const float*)d_in[0];
    const float* proj = (const float*)d_in[1];
    const float* img[2] = {(const float*)d_in[2], (const float*)d_in[3]};
    const float* vol[2] = {(const float*)d_in[4], (const float*)d_in[5]};
    const float* Wf[4] = {(const float*)d_in[6], (const float*)d_in[8], (const float*)d_in[10], (const float*)d_in[12]};
    const float* bf[4] = {(const float*)d_in[7], (const float*)d_in[9], (const float*)d_in[11], (const float*)d_in[13]};
    const float* W4 = (const float*)d_in[14];
    const float* b4 = (const float*)d_in[15];
    const int* mn = (const int*)d_in[16];
    float* out = (float*)d_out;

    const int Kp[4] = {320, 1344, 832, 576};
    const int Msz[4] = {1024, 512, 256, 128};

    char* ws = (char*)d_ws;
    size_t off = 0;
    auto alloc = [&](size_t bytes) -> char* {
        char* p = ws + off;
        off = (off + bytes + 255) & ~(size_t)255;
        return p;
    };

    const size_t imgStride = (size_t)NV * HH * WWW * C2C;
    const size_t volStride = (size_t)NV * 32768 * C3C;

    unsigned short* Wb[4];
    for (int i = 0; i < 4; i++) Wb[i] = (unsigned short*)alloc((size_t)Msz[i] * Kp[i] * 2);
    unsigned short* imgT = (unsigned short*)alloc(2 * imgStride * 2);
    unsigned short* volT = (unsigned short*)alloc(2 * volStride * 2);
    size_t fixed = off;

    const size_t perPt = (size_t)NV * 2 * (CINP + 1024 + 512);
    int Nk = NPTS;
    if (fixed + (size_t)Nk * perPt + 4096 > ws_size) {
        size_t avail = (ws_size > fixed + 4096) ? (ws_size - fixed - 4096) : 0;
        long nk = (long)(avail / perPt);
        nk = (nk / 512) * 512;
        if (nk < 512) nk = 512;
        if (nk > NPTS) nk = NPTS;
        Nk = (int)nk;
    }
    unsigned short* ptT = (unsigned short*)alloc((size_t)NV * Nk * CINP * 2);
    unsigned short* o0 = (unsigned short*)alloc((size_t)NV * Nk * 1024 * 2);
    unsigned short* o1 = (unsigned short*)alloc((size_t)NV * Nk * 512 * 2);
    unsigned short* o2 = o0;                          // alias: o0 dead once g2 runs
    unsigned short* o3 = o0 + (size_t)NV * Nk * 256;  // alias: after o2 region

    k_wpad4<<<dim3(2688, 4), 256, 0, stream>>>(Wf[0], Wf[1], Wf[2], Wf[3], Wb[0], Wb[1], Wb[2], Wb[3]);
    k_timg<<<dim3(NV * HH, WWW / 64, 8), 256, 0, stream>>>(img[0], img[1], imgT, imgStride);
    k_tvol<<<dim3(NV, 32768 / 256, 2), 256, 0, stream>>>(vol[0], vol[1], volT, volStride);

    for (int n0 = 0; n0 < NPTS; n0 += Nk) {
        int nk = NPTS - n0 < Nk ? NPTS - n0 : Nk;
        int NC = NV * nk;
        // level 0
        k_sampleL0<<<dim3(nk / 4, NV), 256, 0, stream>>>(pts, proj, imgT, volT, ptT, n0, nk);
        k_g0L0<<<dim3(1024 / 128, NC / 128), 256, 0, stream>>>(Wb[0], ptT, bf[0], o0);
        k_g1L0<<<dim3(512 / 256, NC / 256), 512, 0, stream>>>(Wb[1], ptT, o0, bf[1], o1);
        k_g2L0<<<dim3(256 / 128, NC / 128), 256, 0, stream>>>(Wb[2], ptT, o1, bf[2], o2);
        k_g3L0<<<dim3(128 / 128, NC / 128), 256, 0, stream>>>(Wb[3], ptT, o2, bf[3], o3);
        k_headL0<<<(nk + 15) / 16, 256, 0, stream>>>(o3, W4, b4, mn, out, n0, nk);
        // level 1
        k_sampleL1<<<dim3(nk / 4, NV), 256, 0, stream>>>(pts, proj, imgT + imgStride, volT + volStride, ptT, n0, nk);
        k_g0L1<<<dim3(1024 / 128, NC / 128), 256, 0, stream>>>(Wb[0], ptT, bf[0], o0);
        k_g1L1<<<dim3(512 / 256, NC / 256), 512, 0, stream>>>(Wb[1], ptT, o0, bf[1], o1);
        k_g2L1<<<dim3(256 / 128, NC / 128), 256, 0, stream>>>(Wb[2], ptT, o1, bf[2], o2);
        k_g3L1<<<dim3(128 / 128, NC / 128), 256, 0, stream>>>(Wb[3], ptT, o2, bf[3], o3);
        k_headL1<<<(nk + 15) / 16, 256, 0, stream>>>(o3, W4, b4, mn, out, n0, nk);
    }
}